// Round 1
// baseline (1084.686 us; speedup 1.0000x reference)
//
#include <hip/hip_runtime.h>

#define HD   64
#define NSEQ 1024
#define NHBH 32          // B*H = 2*16

// ---------------------------------------------------------------------------
// Kernel 1: per-token depthwise conv of key/value with emb-gathered kernels.
// Produces 6 tensors (bh, n, f) fp32 in ws:
//   key_c (j=0, all 5 taps), key_j1 (taps 0..3), key_j2 (taps 0..2)
//   val_c, val_j1, val_j2
// tap k reads position n + k - 2 (zero-padded).
// ---------------------------------------------------------------------------
__global__ __launch_bounds__(256) void conv_kernel(
    const int* __restrict__ ids,
    const float* __restrict__ keyg,
    const float* __restrict__ valg,
    const float* __restrict__ emb,
    float* __restrict__ key_c, float* __restrict__ val_c,
    float* __restrict__ key_j1, float* __restrict__ key_j2,
    float* __restrict__ val_j1, float* __restrict__ val_j2)
{
    int idx = blockIdx.x * 256 + threadIdx.x;   // (bh, n, f) row-major, 2^21 total
    int f  = idx & 63;
    int n  = (idx >> 6) & (NSEQ - 1);
    int bh = idx >> 16;                          // b*16+h
    int b  = bh >> 4;

    int id = ids[b * NSEQ + n];
    const float* e = emb + (size_t)id * 10;
    float c0 = e[0], c1 = e[1], c2 = e[2], c3 = e[3], c4 = e[4];
    float d0 = e[5], d1 = e[6], d2 = e[7], d3 = e[8], d4 = e[9];

    const float* kb = keyg + (size_t)bh * NSEQ * HD + f;
    const float* vb = valg + (size_t)bh * NSEQ * HD + f;

    float xk[5], xv[5];
#pragma unroll
    for (int k = 0; k < 5; ++k) {
        int m = n + k - 2;
        bool ok = (m >= 0) && (m < NSEQ);
        xk[k] = ok ? kb[(size_t)m * HD] : 0.f;
        xv[k] = ok ? vb[(size_t)m * HD] : 0.f;
    }

    float k012 = c0 * xk[0] + c1 * xk[1] + c2 * xk[2];
    float v012 = d0 * xv[0] + d1 * xv[1] + d2 * xv[2];
    float k3 = c3 * xk[3], k4 = c4 * xk[4];
    float v3 = d3 * xv[3], v4 = d4 * xv[4];

    size_t o = (size_t)idx;
    key_c [o] = k012 + k3 + k4;
    val_c [o] = v012 + v3 + v4;
    key_j1[o] = k012 + k3;
    key_j2[o] = k012;
    val_j1[o] = v012 + v3;
    val_j2[o] = v012;
}

// ---------------------------------------------------------------------------
// Kernel 2: causal attention, one block per (bh, n) query row.
// Diagonal substitution: col m==n uses j=2 conv rows, m==n-1 uses j=1 rows
// (for both key in the score and value in PV) — equivalent to the reference's
// scores .set() + post-softmax value correction.
// ---------------------------------------------------------------------------
__global__ __launch_bounds__(256) void attn_kernel(
    const float* __restrict__ qg,
    const float* __restrict__ key_c, const float* __restrict__ val_c,
    const float* __restrict__ key_j1, const float* __restrict__ key_j2,
    const float* __restrict__ val_j1, const float* __restrict__ val_j2,
    float* __restrict__ outg)
{
    int row = blockIdx.x;          // bh*NSEQ + n
    int n   = row & (NSEQ - 1);
    int bh  = row >> 10;
    int t   = threadIdx.x;

    __shared__ float qs[HD];
    __shared__ float sc[NSEQ];
    __shared__ float red[8];
    __shared__ float pv[4][HD];

    if (t < HD) qs[t] = qg[(size_t)row * HD + t] * 0.125f;  // 1/sqrt(64)
    __syncthreads();

    size_t base = (size_t)bh * NSEQ * HD;

    // --- scores + local max ---
    float lmax = -1e30f;
    for (int m = t; m <= n; m += 256) {
        const float* kr;
        if (m == n)          kr = key_j2 + base + (size_t)m * HD;
        else if (m == n - 1) kr = key_j1 + base + (size_t)m * HD;
        else                 kr = key_c  + base + (size_t)m * HD;
        float s = 0.f;
#pragma unroll
        for (int f = 0; f < HD; ++f) s += qs[f] * kr[f];
        sc[m] = s;
        lmax = fmaxf(lmax, s);
    }
#pragma unroll
    for (int o2 = 32; o2 > 0; o2 >>= 1)
        lmax = fmaxf(lmax, __shfl_down(lmax, o2, 64));
    if ((t & 63) == 0) red[t >> 6] = lmax;
    __syncthreads();
    float gmax = fmaxf(fmaxf(red[0], red[1]), fmaxf(red[2], red[3]));

    // --- exp + local sum ---
    float lsum = 0.f;
    for (int m = t; m <= n; m += 256) {
        float p = __expf(sc[m] - gmax);
        sc[m] = p;
        lsum += p;
    }
#pragma unroll
    for (int o2 = 32; o2 > 0; o2 >>= 1)
        lsum += __shfl_down(lsum, o2, 64);
    if ((t & 63) == 0) red[4 + (t >> 6)] = lsum;
    __syncthreads();
    float gsum = red[4] + red[5] + red[6] + red[7];

    // --- PV with diagonal value substitution ---
    int f = t & 63;
    int c = t >> 6;
    float acc = 0.f;
    for (int m = c; m <= n; m += 4) {
        const float* vr;
        if (m == n)          vr = val_j2 + base + (size_t)m * HD;
        else if (m == n - 1) vr = val_j1 + base + (size_t)m * HD;
        else                 vr = val_c  + base + (size_t)m * HD;
        acc += sc[m] * vr[f];
    }
    pv[c][f] = acc;
    __syncthreads();
    if (c == 0) {
        float r = (pv[0][f] + pv[1][f] + pv[2][f] + pv[3][f]) / gsum;
        outg[(size_t)row * HD + f] = r;
    }
}

extern "C" void kernel_launch(void* const* d_in, const int* in_sizes, int n_in,
                              void* d_out, int out_size, void* d_ws, size_t ws_size,
                              hipStream_t stream)
{
    const int*   ids = (const int*)  d_in[0];
    const float* q   = (const float*)d_in[1];
    const float* key = (const float*)d_in[2];
    const float* val = (const float*)d_in[3];
    const float* emb = (const float*)d_in[4];
    float* out = (float*)d_out;

    float* w = (float*)d_ws;
    size_t S = (size_t)NHBH * NSEQ * HD;   // 2,097,152 floats per tensor
    float* key_c  = w;
    float* val_c  = w + S;
    float* key_j1 = w + 2 * S;
    float* key_j2 = w + 3 * S;
    float* val_j1 = w + 4 * S;
    float* val_j2 = w + 5 * S;

    int conv_blocks = (int)(S / 256);      // 8192
    conv_kernel<<<conv_blocks, 256, 0, stream>>>(
        ids, key, val, emb, key_c, val_c, key_j1, key_j2, val_j1, val_j2);

    int attn_blocks = NHBH * NSEQ;         // 32768
    attn_kernel<<<attn_blocks, 256, 0, stream>>>(
        q, key_c, val_c, key_j1, key_j2, val_j1, val_j2, out);
}

// Round 2
// 62.682 us; speedup vs baseline: 17.3046x; 17.3046x over previous
//
#include <hip/hip_runtime.h>

#define HD   64
#define NSEQ 1024
#define NBH  32          // B*H = 2*16

typedef __attribute__((ext_vector_type(8))) __bf16 bf16x8;
typedef __attribute__((ext_vector_type(4))) float  f32x4;

__device__ inline unsigned short f2bf(float x) {
    unsigned u = __float_as_uint(x);
    unsigned r = (u + 0x7fffu + ((u >> 16) & 1u)) >> 16;
    return (unsigned short)r;
}
__device__ inline unsigned pk2(float a, float b) {
    return (unsigned)f2bf(a) | ((unsigned)f2bf(b) << 16);
}

// ---------------------------------------------------------------------------
// Kernel 1: conv. Per block: one bh, 64 n rows. Outputs:
//  kc  [bh][n][f] bf16 (ushort), vcT [bh][f][n] bf16, vd1/vd2 [bh][n][f] fp32
// ---------------------------------------------------------------------------
__global__ __launch_bounds__(256) void conv_kernel(
    const int* __restrict__ ids,
    const float* __restrict__ keyg,
    const float* __restrict__ valg,
    const float* __restrict__ emb,
    unsigned short* __restrict__ kc,
    unsigned short* __restrict__ vcT,
    float* __restrict__ vd1, float* __restrict__ vd2)
{
    __shared__ float vtile[64][65];
    int bh = blockIdx.x >> 4;
    int n0 = (blockIdx.x & 15) << 6;
    int b  = bh >> 4;
    int t  = threadIdx.x;
    const float* kb = keyg + (size_t)bh * NSEQ * HD;
    const float* vb = valg + (size_t)bh * NSEQ * HD;

#pragma unroll
    for (int i = 0; i < 16; ++i) {
        int e  = t + (i << 8);
        int nl = e >> 6, f = e & 63;
        int n  = n0 + nl;
        int id = ids[b * NSEQ + n];
        const float* em = emb + (size_t)id * 10;
        float xk[5], xv[5];
#pragma unroll
        for (int k = 0; k < 5; ++k) {
            int m = n + k - 2;
            bool ok = (m >= 0) && (m < NSEQ);
            xk[k] = ok ? kb[(size_t)m * HD + f] : 0.f;
            xv[k] = ok ? vb[(size_t)m * HD + f] : 0.f;
        }
        float kcv = em[0]*xk[0] + em[1]*xk[1] + em[2]*xk[2] + em[3]*xk[3] + em[4]*xk[4];
        float vcv = em[5]*xv[0] + em[6]*xv[1] + em[7]*xv[2] + em[8]*xv[3] + em[9]*xv[4];
        float v1  = -em[9]*xv[4];
        float v2  = v1 - em[8]*xv[3];
        size_t o  = (size_t)bh * NSEQ * HD + (size_t)n * HD + f;
        kc [o] = f2bf(kcv);
        vd1[o] = v1;
        vd2[o] = v2;
        vtile[nl][f] = vcv;
    }
    __syncthreads();
#pragma unroll
    for (int i = 0; i < 16; ++i) {
        int e  = t + (i << 8);
        int f  = e >> 6, nl = e & 63;
        vcT[((size_t)bh * HD + f) * NSEQ + n0 + nl] = f2bf(vtile[nl][f]);
    }
}

// ---------------------------------------------------------------------------
// Kernel 2: diagonal scores (fp32). One wave per (bh,n).
//  diag2[row] = scale * q[n]·key_j2[n] ;  diag1[row] = scale * q[n]·key_j1[n-1]
// ---------------------------------------------------------------------------
__global__ __launch_bounds__(256) void diag_kernel(
    const int* __restrict__ ids,
    const float* __restrict__ qg,
    const float* __restrict__ keyg,
    const float* __restrict__ emb,
    float* __restrict__ dg1, float* __restrict__ dg2)
{
    int t = threadIdx.x, f = t & 63, w = t >> 6;
    int row = blockIdx.x * 4 + w;           // 0..32767
    int n  = row & (NSEQ - 1);
    int bh = row >> 10;
    int b  = bh >> 4;
    const float* kb = keyg + (size_t)bh * NSEQ * HD + f;
    float qf = qg[((size_t)bh * NSEQ + n) * HD + f] * 0.125f;
    float x0  = kb[(size_t)n * HD];
    float xm1 = (n >= 1) ? kb[(size_t)(n-1) * HD] : 0.f;
    float xm2 = (n >= 2) ? kb[(size_t)(n-2) * HD] : 0.f;
    float xm3 = (n >= 3) ? kb[(size_t)(n-3) * HD] : 0.f;
    const float* e = emb + (size_t)ids[b * NSEQ + n] * 10;
    float s2 = qf * (e[0]*xm2 + e[1]*xm1 + e[2]*x0);
    float s1 = 0.f;
    if (n >= 1) {
        const float* e1 = emb + (size_t)ids[b * NSEQ + n - 1] * 10;
        s1 = qf * (e1[0]*xm3 + e1[1]*xm2 + e1[2]*xm1 + e1[3]*x0);
    }
#pragma unroll
    for (int o = 1; o < 64; o <<= 1) {
        s2 += __shfl_xor(s2, o, 64);
        s1 += __shfl_xor(s1, o, 64);
    }
    if (f == 0) { dg2[row] = s2; dg1[row] = s1; }
}

// ---------------------------------------------------------------------------
// Kernel 3: MFMA flash attention + diagonal fixups.
// Block: 256 thr (4 waves), QB=64 (16 q rows/wave). KV tiles of 64.
// LDS tiles XOR-swizzled per 16B chunk: byte = row*128 + ((chunk ^ (row&7))<<4)
// ---------------------------------------------------------------------------
__global__ __launch_bounds__(256) void attn_kernel(
    const float* __restrict__ qg,
    const unsigned short* __restrict__ kc,
    const unsigned short* __restrict__ vcT,
    const float* __restrict__ vd1, const float* __restrict__ vd2,
    const float* __restrict__ dg1, const float* __restrict__ dg2,
    float* __restrict__ outg)
{
    __shared__ __align__(16) unsigned char sK[8192];
    __shared__ __align__(16) unsigned char sV[8192];
    __shared__ __align__(16) unsigned char sP[8192];

    int bid = blockIdx.x;
    int bh  = bid >> 4;
    int q0  = (15 - (bid & 15)) << 6;      // heavy blocks first
    int t   = threadIdx.x;
    int w   = t >> 6, l = t & 63;
    int lq  = l & 15, h = l >> 4, l7 = l & 7;
    int qbw = q0 + w * 16;
    size_t hb = (size_t)bh * NSEQ * HD;

    const unsigned short* kcb = kc  + hb;
    const unsigned short* vtb = vcT + (size_t)bh * HD * NSEQ;

    // Q fragments (B operand; pre-scaled)
    bf16x8 qb0, qb1;
    {
        const float* qr = qg + hb + (size_t)(qbw + lq) * HD;
        union { unsigned short s[8]; bf16x8 v; } u0, u1;
#pragma unroll
        for (int e = 0; e < 8; ++e) {
            u0.s[e] = f2bf(qr[8 * h + e]      * 0.125f);
            u1.s[e] = f2bf(qr[32 + 8 * h + e] * 0.125f);
        }
        qb0 = u0.v; qb1 = u1.v;
    }
    float diag2_l = dg2[bh * NSEQ + qbw + lq];
    float diag1_l = dg1[bh * NSEQ + qbw + lq];

    f32x4 of[4];
#pragma unroll
    for (int ft = 0; ft < 4; ++ft) of[ft] = (f32x4){0.f, 0.f, 0.f, 0.f};
    float m_run = -1e30f, denom = 0.f;

    const int ka_off0 = ((0 + h) ^ l7) << 4;   // chunk 4*kk+h, kk=0
    const int ka_off1 = ((4 + h) ^ l7) << 4;   // kk=1
    const int pr_base = w * 2048 + lq * 128;
    const int nt   = (q0 >> 6) + 1;
    const int chk0 = ((qbw > 0 ? qbw - 1 : 0) >> 6);   // substitution window start

    for (int tI = 0; tI < nt; ++tI) {
        int kv0 = tI << 6;
        // ---- stage K tile + V^T tile (source-swizzled, linear LDS dest) ----
#pragma unroll
        for (int i = 0; i < 4; ++i) {
            int chunk = t + (i << 8);
            int buf = chunk >> 9, loc = chunk & 511;
            int r = loc >> 3, c = loc & 7;
            int cs = c ^ (r & 7);
            uint4 v;
            if (buf == 0) v = *(const uint4*)(kcb + (size_t)(kv0 + r) * HD + cs * 8);
            else          v = *(const uint4*)(vtb + (size_t)r * NSEQ + kv0 + cs * 8);
            *(uint4*)((buf ? sV : sK) + r * 128 + c * 16) = v;
        }
        __syncthreads();

        // ---- QK^T (swapped: D[kv][q]) ----
        f32x4 p[4];
#pragma unroll
        for (int st = 0; st < 4; ++st) {
            bf16x8 ka0 = *(const bf16x8*)(sK + st * 2048 + lq * 128 + ka_off0);
            bf16x8 ka1 = *(const bf16x8*)(sK + st * 2048 + lq * 128 + ka_off1);
            f32x4 d = (f32x4){0.f, 0.f, 0.f, 0.f};
            d = __builtin_amdgcn_mfma_f32_16x16x32_bf16(ka0, qb0, d, 0, 0, 0);
            d = __builtin_amdgcn_mfma_f32_16x16x32_bf16(ka1, qb1, d, 0, 0, 0);
            p[st] = d;
        }

        // ---- mask + diagonal substitution (last two tiles only) ----
        if (tI >= chk0) {
            int n_l = qbw + lq;
#pragma unroll
            for (int st = 0; st < 4; ++st)
#pragma unroll
                for (int r = 0; r < 4; ++r) {
                    int kv = kv0 + st * 16 + 4 * h + r;
                    float dd = p[st][r];
                    if (kv > n_l)          dd = -1e30f;
                    else if (kv == n_l)     dd = diag2_l;
                    else if (kv == n_l - 1) dd = diag1_l;
                    p[st][r] = dd;
                }
        }

        // ---- online softmax update ----
        float tmax = -1e30f;
#pragma unroll
        for (int st = 0; st < 4; ++st)
#pragma unroll
            for (int r = 0; r < 4; ++r) tmax = fmaxf(tmax, p[st][r]);
        tmax = fmaxf(tmax, __shfl_xor(tmax, 16, 64));
        tmax = fmaxf(tmax, __shfl_xor(tmax, 32, 64));
        float m_new = fmaxf(m_run, tmax);
        float alpha = __expf(m_run - m_new);
        float lsum = 0.f;
#pragma unroll
        for (int st = 0; st < 4; ++st)
#pragma unroll
            for (int r = 0; r < 4; ++r) {
                float e = __expf(p[st][r] - m_new);
                p[st][r] = e;
                lsum += e;
            }
        lsum += __shfl_xor(lsum, 16, 64);
        lsum += __shfl_xor(lsum, 32, 64);
        denom = denom * alpha + lsum;
        m_run = m_new;
#pragma unroll
        for (int r = 0; r < 4; ++r) {
            float ar = __shfl(alpha, 4 * h + r, 64);
            of[0][r] *= ar; of[1][r] *= ar; of[2][r] *= ar; of[3][r] *= ar;
        }

        // ---- P -> bf16 into per-wave LDS (swizzled like sK/sV rows) ----
#pragma unroll
        for (int st = 0; st < 4; ++st) {
            uint2 uu;
            uu.x = pk2(p[st][0], p[st][1]);
            uu.y = pk2(p[st][2], p[st][3]);
            int chunk = (st << 1) + (h >> 1);
            *(uint2*)(sP + pr_base + ((chunk ^ l7) << 4) + ((h & 1) << 3)) = uu;
        }
        asm volatile("s_waitcnt lgkmcnt(0)" ::: "memory");
        __builtin_amdgcn_sched_barrier(0);

        // ---- PV: O[q][f] += P·V ----
#pragma unroll
        for (int kk = 0; kk < 2; ++kk) {
            int koff = kk ? ka_off1 : ka_off0;
            bf16x8 pa = *(const bf16x8*)(sP + pr_base + koff);
#pragma unroll
            for (int ft = 0; ft < 4; ++ft) {
                bf16x8 vb = *(const bf16x8*)(sV + ft * 2048 + lq * 128 + koff);
                of[ft] = __builtin_amdgcn_mfma_f32_16x16x32_bf16(pa, vb, of[ft], 0, 0, 0);
            }
        }
        __syncthreads();
    }

    // ---- epilogue: normalize + diagonal value corrections ----
    const float* vd1r = vd1 + hb;
    const float* vd2r = vd2 + hb;
    float* outr = outg + hb;
#pragma unroll
    for (int r = 0; r < 4; ++r) {
        int qrow = 4 * h + r;
        float dn = __shfl(denom,   qrow, 64);
        float mf = __shfl(m_run,   qrow, 64);
        float d2 = __shfl(diag2_l, qrow, 64);
        float d1 = __shfl(diag1_l, qrow, 64);
        int n = qbw + qrow;
        float inv = 1.0f / dn;
        float p2 = __expf(d2 - mf) * inv;
        float p1 = (n >= 1) ? __expf(d1 - mf) * inv : 0.f;
#pragma unroll
        for (int ft = 0; ft < 4; ++ft) {
            int f = ft * 16 + lq;
            float val = of[ft][r] * inv + p2 * vd2r[(size_t)n * HD + f];
            if (n >= 1) val += p1 * vd1r[(size_t)(n - 1) * HD + f];
            outr[(size_t)n * HD + f] = val;
        }
    }
}

extern "C" void kernel_launch(void* const* d_in, const int* in_sizes, int n_in,
                              void* d_out, int out_size, void* d_ws, size_t ws_size,
                              hipStream_t stream)
{
    const int*   ids = (const int*)  d_in[0];
    const float* q   = (const float*)d_in[1];
    const float* key = (const float*)d_in[2];
    const float* val = (const float*)d_in[3];
    const float* emb = (const float*)d_in[4];
    float* out = (float*)d_out;

    char* w = (char*)d_ws;
    unsigned short* kc  = (unsigned short*)(w);                    // 4 MB
    unsigned short* vcT = (unsigned short*)(w + (4u << 20));       // 4 MB
    float* vd1 = (float*)(w + (8u  << 20));                        // 8 MB
    float* vd2 = (float*)(w + (16u << 20));                        // 8 MB
    float* dg1 = (float*)(w + (24u << 20));                        // 128 KB
    float* dg2 = (float*)(w + (24u << 20) + (1u << 17));           // 128 KB

    conv_kernel<<<512, 256, 0, stream>>>(ids, key, val, emb, kc, vcT, vd1, vd2);
    diag_kernel<<<8192, 256, 0, stream>>>(ids, q, key, emb, dg1, dg2);
    attn_kernel<<<512, 256, 0, stream>>>(q, kc, vcT, vd1, vd2, dg1, dg2, out);
}

// Round 3
// 59.206 us; speedup vs baseline: 18.3206x; 1.0587x over previous
//
#include <hip/hip_runtime.h>

#define HD   64
#define NSEQ 1024

typedef __attribute__((ext_vector_type(8))) __bf16 bf16x8;
typedef __attribute__((ext_vector_type(4))) float  f32x4;
typedef __attribute__((ext_vector_type(4))) unsigned short u16x4;

__device__ inline unsigned short f2bf(float x) {
    unsigned u = __float_as_uint(x);
    return (unsigned short)((u + 0x7fffu + ((u >> 16) & 1u)) >> 16);
}
__device__ inline unsigned pk2(float a, float b) {
    return (unsigned)f2bf(a) | ((unsigned)f2bf(b) << 16);
}
__device__ inline float dot4(f32x4 a, f32x4 b) {
    return a.x * b.x + a.y * b.y + a.z * b.z + a.w * b.w;
}

// ---------------------------------------------------------------------------
// Kernel 1: conv + diag (fused). Block = one bh x 64 n-rows.
// Outputs: kc [bh][n][f] bf16, vcT [bh][f][n] bf16, dg1/dg2 [bh][n] fp32.
// ---------------------------------------------------------------------------
__global__ __launch_bounds__(256) void conv_kernel(
    const int* __restrict__ ids,
    const float* __restrict__ keyg,
    const float* __restrict__ valg,
    const float* __restrict__ qg,
    const float* __restrict__ emb,
    unsigned short* __restrict__ kc,
    unsigned short* __restrict__ vcT,
    float* __restrict__ dg1, float* __restrict__ dg2)
{
    __shared__ float se[650];          // emb rows for n0-1 .. n0+63
    __shared__ float vtile[64][68];
    int bh = blockIdx.x >> 4;
    int n0 = (blockIdx.x & 15) << 6;
    int b  = bh >> 4;
    int t  = threadIdx.x;
    size_t hb = (size_t)bh * NSEQ * HD;

    for (int u = t; u < 650; u += 256) {
        int r = u / 10, c = u - r * 10;
        int n = n0 - 1 + r;
        se[u] = (n >= 0) ? emb[(size_t)ids[b * NSEQ + n] * 10 + c] : 0.f;
    }
    __syncthreads();

    const float* kb = keyg + hb;
    const float* vb = valg + hb;
#pragma unroll
    for (int i = 0; i < 4; ++i) {
        int u  = (i << 8) + t;
        int nl = u >> 4, g4 = u & 15;
        int n  = n0 + nl, f = g4 << 2;
        const float* e  = se + (nl + 1) * 10;
        const float* ep = se + nl * 10;
        f32x4 xk[5], xv[5];
#pragma unroll
        for (int k = 0; k < 5; ++k) {
            int m = n + k - 2;
            if (m >= 0 && m < NSEQ) {
                xk[k] = *(const f32x4*)(kb + (size_t)m * HD + f);
                xv[k] = *(const f32x4*)(vb + (size_t)m * HD + f);
            } else {
                xk[k] = (f32x4){0.f, 0.f, 0.f, 0.f};
                xv[k] = (f32x4){0.f, 0.f, 0.f, 0.f};
            }
        }
        f32x4 km3 = (n >= 3) ? *(const f32x4*)(kb + (size_t)(n - 3) * HD + f)
                             : (f32x4){0.f, 0.f, 0.f, 0.f};
        f32x4 qv = *(const f32x4*)(qg + hb + (size_t)n * HD + f) * 0.125f;

        f32x4 k012 = e[0] * xk[0] + e[1] * xk[1] + e[2] * xk[2];
        f32x4 kcv  = k012 + e[3] * xk[3] + e[4] * xk[4];
        f32x4 vcv  = e[5] * xv[0] + e[6] * xv[1] + e[7] * xv[2] + e[8] * xv[3] + e[9] * xv[4];

        u16x4 kq;
        kq.x = f2bf(kcv.x); kq.y = f2bf(kcv.y); kq.z = f2bf(kcv.z); kq.w = f2bf(kcv.w);
        *(u16x4*)(kc + hb + (size_t)n * HD + f) = kq;
        *(f32x4*)(&vtile[nl][f]) = vcv;

        float s2 = dot4(qv, k012);
        f32x4 kj1 = ep[0] * km3 + ep[1] * xk[0] + ep[2] * xk[1] + ep[3] * xk[2];
        float s1 = dot4(qv, kj1);
#pragma unroll
        for (int o = 1; o < 16; o <<= 1) {
            s2 += __shfl_xor(s2, o, 64);
            s1 += __shfl_xor(s1, o, 64);
        }
        if (g4 == 0) {
            dg2[bh * NSEQ + n] = s2;
            dg1[bh * NSEQ + n] = s1;
        }
    }
    __syncthreads();
#pragma unroll
    for (int i = 0; i < 4; ++i) {
        int u = (i << 8) + t;
        int f = u >> 4, nn = (u & 15) << 2;
        u16x4 o;
        o.x = f2bf(vtile[nn + 0][f]);
        o.y = f2bf(vtile[nn + 1][f]);
        o.z = f2bf(vtile[nn + 2][f]);
        o.w = f2bf(vtile[nn + 3][f]);
        *(u16x4*)(vcT + ((size_t)bh * HD + f) * NSEQ + n0 + nn) = o;
    }
}

// ---------------------------------------------------------------------------
// Kernel 2: MFMA flash attention + diagonal fixups. 4 waves, QB=64, KV=64.
// Reg-prefetch staging; defer-rescale online softmax; val-based epilogue.
// ---------------------------------------------------------------------------
__global__ __launch_bounds__(256) void attn_kernel(
    const float* __restrict__ qg,
    const unsigned short* __restrict__ kc,
    const unsigned short* __restrict__ vcT,
    const float* __restrict__ valg,
    const int* __restrict__ ids,
    const float* __restrict__ emb,
    const float* __restrict__ dg1, const float* __restrict__ dg2,
    float* __restrict__ outg)
{
    __shared__ __align__(16) unsigned char sK[8192];
    __shared__ __align__(16) unsigned char sV[8192];
    __shared__ __align__(16) unsigned char sP[8192];

    int bid = blockIdx.x;
    int bh  = bid & 31;
    int q0  = (15 - (bid >> 5)) << 6;      // LPT: heavy q-tiles dispatched first
    int t   = threadIdx.x;
    int w   = t >> 6, l = t & 63;
    int lq  = l & 15, h = l >> 4, l7 = l & 7;
    int qbw = q0 + w * 16;
    size_t hb = (size_t)bh * NSEQ * HD;

    const unsigned short* kcb = kc  + hb;
    const unsigned short* vtb = vcT + (size_t)bh * HD * NSEQ;

    // Q fragments (B operand; pre-scaled), vectorized load
    bf16x8 qb0, qb1;
    {
        const float* qr = qg + hb + (size_t)(qbw + lq) * HD + 8 * h;
        f32x4 a0 = *(const f32x4*)(qr);
        f32x4 a1 = *(const f32x4*)(qr + 4);
        f32x4 b0 = *(const f32x4*)(qr + 32);
        f32x4 b1 = *(const f32x4*)(qr + 36);
        const float S = 0.125f;
        union { unsigned u[4]; bf16x8 v; } u0, u1;
        u0.u[0] = pk2(a0.x * S, a0.y * S); u0.u[1] = pk2(a0.z * S, a0.w * S);
        u0.u[2] = pk2(a1.x * S, a1.y * S); u0.u[3] = pk2(a1.z * S, a1.w * S);
        u1.u[0] = pk2(b0.x * S, b0.y * S); u1.u[1] = pk2(b0.z * S, b0.w * S);
        u1.u[2] = pk2(b1.x * S, b1.y * S); u1.u[3] = pk2(b1.z * S, b1.w * S);
        qb0 = u0.v; qb1 = u1.v;
    }
    float diag2_l = dg2[bh * NSEQ + qbw + lq];
    float diag1_l = dg1[bh * NSEQ + qbw + lq];

    f32x4 of[4];
#pragma unroll
    for (int ft = 0; ft < 4; ++ft) of[ft] = (f32x4){0.f, 0.f, 0.f, 0.f};
    float m_run = -1e30f, denom = 0.f;

    const int ka_off0 = ((0 + h) ^ l7) << 4;
    const int ka_off1 = ((4 + h) ^ l7) << 4;
    const int pr_base = w * 2048 + lq * 128;
    const int nt   = (q0 >> 6) + 1;
    const int chk0 = ((qbw > 0 ? qbw - 1 : 0) >> 6);

    uint4 pf[4];
    auto issue = [&](int tI) {
        int kv0 = tI << 6;
#pragma unroll
        for (int i = 0; i < 4; ++i) {
            int chunk = t + (i << 8);
            int buf = chunk >> 9, loc = chunk & 511;
            int r = loc >> 3, c = loc & 7;
            int cs = c ^ (r & 7);
            pf[i] = (buf == 0)
                ? *(const uint4*)(kcb + (size_t)(kv0 + r) * HD + cs * 8)
                : *(const uint4*)(vtb + (size_t)r * NSEQ + kv0 + cs * 8);
        }
    };
    auto commit = [&]() {
#pragma unroll
        for (int i = 0; i < 4; ++i) {
            int chunk = t + (i << 8);
            int buf = chunk >> 9, loc = chunk & 511;
            int r = loc >> 3, c = loc & 7;
            *(uint4*)((buf ? sV : sK) + r * 128 + c * 16) = pf[i];
        }
    };

    issue(0); commit();
    for (int tI = 0; tI < nt; ++tI) {
        __syncthreads();                       // staged tile visible
        if (tI + 1 < nt) issue(tI + 1);        // prefetch next tile (hidden)
        int kv0 = tI << 6;

        // ---- QK^T (swapped: D[kv][q]) ----
        f32x4 p[4];
#pragma unroll
        for (int st = 0; st < 4; ++st) {
            bf16x8 ka0 = *(const bf16x8*)(sK + st * 2048 + lq * 128 + ka_off0);
            bf16x8 ka1 = *(const bf16x8*)(sK + st * 2048 + lq * 128 + ka_off1);
            f32x4 d = (f32x4){0.f, 0.f, 0.f, 0.f};
            d = __builtin_amdgcn_mfma_f32_16x16x32_bf16(ka0, qb0, d, 0, 0, 0);
            d = __builtin_amdgcn_mfma_f32_16x16x32_bf16(ka1, qb1, d, 0, 0, 0);
            p[st] = d;
        }

        // ---- mask + diagonal substitution (trailing tiles only) ----
        if (tI >= chk0) {
            int n_l = qbw + lq;
#pragma unroll
            for (int st = 0; st < 4; ++st)
#pragma unroll
                for (int r = 0; r < 4; ++r) {
                    int kv = kv0 + st * 16 + 4 * h + r;
                    float dd = p[st][r];
                    if (kv > n_l)           dd = -1e30f;
                    else if (kv == n_l)     dd = diag2_l;
                    else if (kv == n_l - 1) dd = diag1_l;
                    p[st][r] = dd;
                }
        }

        // ---- online softmax with defer-rescale (THR=5) ----
        float tmax = -1e30f;
#pragma unroll
        for (int st = 0; st < 4; ++st)
#pragma unroll
            for (int r = 0; r < 4; ++r) tmax = fmaxf(tmax, p[st][r]);
        tmax = fmaxf(tmax, __shfl_xor(tmax, 16, 64));
        tmax = fmaxf(tmax, __shfl_xor(tmax, 32, 64));
        if (!__all(tmax <= m_run + 5.0f)) {
            float m_new = fmaxf(m_run, tmax);
            float alpha = __expf(m_run - m_new);
            denom *= alpha;
            m_run = m_new;
#pragma unroll
            for (int r = 0; r < 4; ++r) {
                float ar = __shfl(alpha, 4 * h + r, 64);
                of[0][r] *= ar; of[1][r] *= ar; of[2][r] *= ar; of[3][r] *= ar;
            }
        }
        float lsum = 0.f;
#pragma unroll
        for (int st = 0; st < 4; ++st)
#pragma unroll
            for (int r = 0; r < 4; ++r) {
                float e = __expf(p[st][r] - m_run);
                p[st][r] = e;
                lsum += e;
            }
        lsum += __shfl_xor(lsum, 16, 64);
        lsum += __shfl_xor(lsum, 32, 64);
        denom += lsum;

        // ---- P -> bf16 into per-wave LDS ----
#pragma unroll
        for (int st = 0; st < 4; ++st) {
            uint2 uu;
            uu.x = pk2(p[st][0], p[st][1]);
            uu.y = pk2(p[st][2], p[st][3]);
            int chunk = (st << 1) + (h >> 1);
            *(uint2*)(sP + pr_base + ((chunk ^ l7) << 4) + ((h & 1) << 3)) = uu;
        }
        asm volatile("s_waitcnt lgkmcnt(0)" ::: "memory");
        __builtin_amdgcn_sched_barrier(0);

        // ---- PV ----
#pragma unroll
        for (int kk = 0; kk < 2; ++kk) {
            int koff = kk ? ka_off1 : ka_off0;
            bf16x8 pa = *(const bf16x8*)(sP + pr_base + koff);
#pragma unroll
            for (int ft = 0; ft < 4; ++ft) {
                bf16x8 vb = *(const bf16x8*)(sV + ft * 2048 + lq * 128 + koff);
                of[ft] = __builtin_amdgcn_mfma_f32_16x16x32_bf16(pa, vb, of[ft], 0, 0, 0);
            }
        }
        __syncthreads();                       // all waves done reading tile
        if (tI + 1 < nt) commit();             // write prefetched tile
    }

    // ---- epilogue: normalize + diagonal value corrections from raw val ----
    const float* vraw = valg + hb;
    float* outr = outg + hb;
    const int* idb = ids + (size_t)(bh >> 4) * NSEQ;
#pragma unroll
    for (int r = 0; r < 4; ++r) {
        int qrow = 4 * h + r;
        float dn = __shfl(denom,   qrow, 64);
        float mf = __shfl(m_run,   qrow, 64);
        float d2 = __shfl(diag2_l, qrow, 64);
        float d1 = __shfl(diag1_l, qrow, 64);
        int n = qbw + qrow;
        float inv = 1.0f / dn;
        float p2 = __expf(d2 - mf) * inv;
        float p1 = (n >= 1) ? __expf(d1 - mf) * inv : 0.f;
        int   id_n = idb[n];
        float e8  = emb[(size_t)id_n * 10 + 8];
        float e9  = emb[(size_t)id_n * 10 + 9];
        float e9p = (n >= 1) ? emb[(size_t)idb[n - 1] * 10 + 9] : 0.f;
        float ca = -(p2 * e8 + p1 * e9p);      // coeff for val[n+1]
        float cb = -p2 * e9;                   // coeff for val[n+2]
#pragma unroll
        for (int ft = 0; ft < 4; ++ft) {
            int f = ft * 16 + lq;
            float val = of[ft][r] * inv;
            if (n + 1 < NSEQ) val += ca * vraw[(size_t)(n + 1) * HD + f];
            if (n + 2 < NSEQ) val += cb * vraw[(size_t)(n + 2) * HD + f];
            outr[(size_t)n * HD + f] = val;
        }
    }
}

extern "C" void kernel_launch(void* const* d_in, const int* in_sizes, int n_in,
                              void* d_out, int out_size, void* d_ws, size_t ws_size,
                              hipStream_t stream)
{
    const int*   ids = (const int*)  d_in[0];
    const float* q   = (const float*)d_in[1];
    const float* key = (const float*)d_in[2];
    const float* val = (const float*)d_in[3];
    const float* emb = (const float*)d_in[4];
    float* out = (float*)d_out;

    char* w = (char*)d_ws;
    unsigned short* kc  = (unsigned short*)(w);                    // 4 MB
    unsigned short* vcT = (unsigned short*)(w + (4u << 20));       // 4 MB
    float* dg1 = (float*)(w + (8u << 20));                         // 128 KB
    float* dg2 = (float*)(w + (8u << 20) + (1u << 17));            // 128 KB

    conv_kernel<<<512, 256, 0, stream>>>(ids, key, val, q, emb, kc, vcT, dg1, dg2);
    attn_kernel<<<512, 256, 0, stream>>>(q, kc, vcT, val, ids, emb, dg1, dg2, out);
}

// Round 4
// 54.290 us; speedup vs baseline: 19.9795x; 1.0905x over previous
//
#include <hip/hip_runtime.h>

#define HD    64
#define NSEQ  1024
#define NSLOT 40
#define CROWS 32

typedef __attribute__((ext_vector_type(8))) __bf16 bf16x8;
typedef __attribute__((ext_vector_type(4))) float  f32x4;
typedef __attribute__((ext_vector_type(4))) unsigned short u16x4;

// (j,c) pairs encoded j*4+c, LPT order: 28 full 4-tile chunks, then len3/2/1.
__device__ __constant__ unsigned char PAIRS[NSLOT] = {
    60,61,62,63, 56,57,58, 52,53,54, 48,49,50, 44,45,46,
    40,41, 36,37, 32,33, 28,29, 24, 20, 16, 12,
    59, 42, 25, 8, 55, 38, 21, 4, 51, 34, 17, 0 };
// reverse map (j*4+c) -> slot
__device__ __constant__ unsigned char IDX[64] = {
    39,255,255,255, 35,255,255,255, 31,255,255,255, 27,255,255,255,
    26, 38,255,255, 25, 34,255,255, 24, 30,255,255, 22, 23,255,255,
    20, 21, 37,255, 18, 19, 33,255, 16, 17, 29,255, 13, 14, 15,255,
    10, 11, 12, 36,  7,  8,  9, 32,  4,  5,  6, 28,  0,  1,  2,  3 };

__device__ inline unsigned short f2bf(float x) {
    unsigned u = __float_as_uint(x);
    return (unsigned short)((u + 0x7fffu + ((u >> 16) & 1u)) >> 16);
}
__device__ inline unsigned pk2(float a, float b) {
    return (unsigned)f2bf(a) | ((unsigned)f2bf(b) << 16);
}
__device__ inline float dot4(f32x4 a, f32x4 b) {
    return a.x * b.x + a.y * b.y + a.z * b.z + a.w * b.w;
}

// ---------------------------------------------------------------------------
// Kernel 1: conv + diag (fused). Block = one bh x 32 n-rows. 1024 blocks.
// ---------------------------------------------------------------------------
__global__ __launch_bounds__(256) void conv_kernel(
    const int* __restrict__ ids,
    const float* __restrict__ keyg,
    const float* __restrict__ valg,
    const float* __restrict__ qg,
    const float* __restrict__ emb,
    unsigned short* __restrict__ kc,
    unsigned short* __restrict__ vcT,
    float* __restrict__ dg1, float* __restrict__ dg2)
{
    __shared__ float se[(CROWS + 1) * 10];
    __shared__ float vtile[CROWS][68];
    int pid = blockIdx.x;
    int bh = pid & 31;
    int n0 = (pid >> 5) * CROWS;
    int b  = bh >> 4;
    int t  = threadIdx.x;
    size_t hb = (size_t)bh * NSEQ * HD;

    for (int u = t; u < (CROWS + 1) * 10; u += 256) {
        int r = u / 10, c = u - r * 10;
        int n = n0 - 1 + r;
        se[u] = (n >= 0) ? emb[(size_t)ids[b * NSEQ + n] * 10 + c] : 0.f;
    }
    __syncthreads();

    const float* kb = keyg + hb;
    const float* vb = valg + hb;
#pragma unroll
    for (int i = 0; i < 2; ++i) {
        int u  = (i << 8) + t;
        int nl = u >> 4, g4 = u & 15;
        int n  = n0 + nl, f = g4 << 2;
        const float* e  = se + (nl + 1) * 10;
        const float* ep = se + nl * 10;
        f32x4 xk[5], xv[5];
#pragma unroll
        for (int k = 0; k < 5; ++k) {
            int m = n + k - 2;
            if (m >= 0 && m < NSEQ) {
                xk[k] = *(const f32x4*)(kb + (size_t)m * HD + f);
                xv[k] = *(const f32x4*)(vb + (size_t)m * HD + f);
            } else {
                xk[k] = (f32x4){0.f, 0.f, 0.f, 0.f};
                xv[k] = (f32x4){0.f, 0.f, 0.f, 0.f};
            }
        }
        f32x4 km3 = (n >= 3) ? *(const f32x4*)(kb + (size_t)(n - 3) * HD + f)
                             : (f32x4){0.f, 0.f, 0.f, 0.f};
        f32x4 qv = *(const f32x4*)(qg + hb + (size_t)n * HD + f) * 0.125f;

        f32x4 k012 = e[0] * xk[0] + e[1] * xk[1] + e[2] * xk[2];
        f32x4 kcv  = k012 + e[3] * xk[3] + e[4] * xk[4];
        f32x4 vcv  = e[5] * xv[0] + e[6] * xv[1] + e[7] * xv[2] + e[8] * xv[3] + e[9] * xv[4];

        u16x4 kq;
        kq.x = f2bf(kcv.x); kq.y = f2bf(kcv.y); kq.z = f2bf(kcv.z); kq.w = f2bf(kcv.w);
        *(u16x4*)(kc + hb + (size_t)n * HD + f) = kq;
        *(f32x4*)(&vtile[nl][f]) = vcv;

        float s2 = dot4(qv, k012);
        f32x4 kj1 = ep[0] * km3 + ep[1] * xk[0] + ep[2] * xk[1] + ep[3] * xk[2];
        float s1 = dot4(qv, kj1);
#pragma unroll
        for (int o = 1; o < 16; o <<= 1) {
            s2 += __shfl_xor(s2, o, 64);
            s1 += __shfl_xor(s1, o, 64);
        }
        if (g4 == 0) {
            dg2[bh * NSEQ + n] = s2;
            dg1[bh * NSEQ + n] = s1;
        }
    }
    __syncthreads();
#pragma unroll
    for (int i = 0; i < 2; ++i) {
        int u = (i << 8) + t;
        int f = u >> 3, nn = (u & 7) << 2;
        u16x4 o;
        o.x = f2bf(vtile[nn + 0][f]);
        o.y = f2bf(vtile[nn + 1][f]);
        o.z = f2bf(vtile[nn + 2][f]);
        o.w = f2bf(vtile[nn + 3][f]);
        *(u16x4*)(vcT + ((size_t)bh * HD + f) * NSEQ + n0 + nn) = o;
    }
}

// ---------------------------------------------------------------------------
// Kernel 2: KV-split MFMA flash attention (partial softmax per chunk).
// Block = (bh, q-tile j, kv-chunk c of <=4 tiles). 1280 blocks, 4 waves.
// ---------------------------------------------------------------------------
__global__ __launch_bounds__(256) void attn_kernel(
    const float* __restrict__ qg,
    const unsigned short* __restrict__ kc,
    const unsigned short* __restrict__ vcT,
    const float* __restrict__ dg1, const float* __restrict__ dg2,
    float* __restrict__ pM, float* __restrict__ pL, float* __restrict__ pO)
{
    __shared__ __align__(16) unsigned char sK[8192];
    __shared__ __align__(16) unsigned char sV[8192];
    __shared__ __align__(16) unsigned char sP[8192];

    int pid  = blockIdx.x;
    int bh   = pid & 31;
    int slot = pid >> 5;
    int code = PAIRS[slot];
    int j = code >> 2, cch = code & 3;
    int q0 = j << 6;
    int t0 = cch << 2;
    int len = j - (cch << 2) + 1; if (len > 4) len = 4;

    int t = threadIdx.x;
    int w = t >> 6, l = t & 63;
    int lq = l & 15, h = l >> 4, l7 = l & 7;
    int qbw = q0 + w * 16;
    size_t hb = (size_t)bh * NSEQ * HD;

    const unsigned short* kcb = kc  + hb;
    const unsigned short* vtb = vcT + (size_t)bh * HD * NSEQ;

    // Q fragments (B operand; pre-scaled)
    bf16x8 qb0, qb1;
    {
        const float* qr = qg + hb + (size_t)(qbw + lq) * HD + 8 * h;
        f32x4 a0 = *(const f32x4*)(qr);
        f32x4 a1 = *(const f32x4*)(qr + 4);
        f32x4 b0 = *(const f32x4*)(qr + 32);
        f32x4 b1 = *(const f32x4*)(qr + 36);
        const float S = 0.125f;
        union { unsigned u[4]; bf16x8 v; } u0, u1;
        u0.u[0] = pk2(a0.x * S, a0.y * S); u0.u[1] = pk2(a0.z * S, a0.w * S);
        u0.u[2] = pk2(a1.x * S, a1.y * S); u0.u[3] = pk2(a1.z * S, a1.w * S);
        u1.u[0] = pk2(b0.x * S, b0.y * S); u1.u[1] = pk2(b0.z * S, b0.w * S);
        u1.u[2] = pk2(b1.x * S, b1.y * S); u1.u[3] = pk2(b1.z * S, b1.w * S);
        qb0 = u0.v; qb1 = u1.v;
    }
    float diag2_l = dg2[bh * NSEQ + qbw + lq];
    float diag1_l = dg1[bh * NSEQ + qbw + lq];

    f32x4 of[4];
#pragma unroll
    for (int ft = 0; ft < 4; ++ft) of[ft] = (f32x4){0.f, 0.f, 0.f, 0.f};
    float m_run = -1e30f, denom = 0.f;

    const int ka_off0 = ((0 + h) ^ l7) << 4;
    const int ka_off1 = ((4 + h) ^ l7) << 4;
    const int pr_base = w * 2048 + lq * 128;
    const int chk0 = ((qbw > 0 ? qbw - 1 : 0) >> 6);

    uint4 pf[4];
    auto issue = [&](int tg) {
        int kv0 = tg << 6;
#pragma unroll
        for (int i = 0; i < 4; ++i) {
            int chunk = t + (i << 8);
            int buf = chunk >> 9, loc = chunk & 511;
            int r = loc >> 3, c = loc & 7;
            int cs = c ^ (r & 7);
            pf[i] = (buf == 0)
                ? *(const uint4*)(kcb + (size_t)(kv0 + r) * HD + cs * 8)
                : *(const uint4*)(vtb + (size_t)r * NSEQ + kv0 + cs * 8);
        }
    };
    auto commit = [&]() {
#pragma unroll
        for (int i = 0; i < 4; ++i) {
            int chunk = t + (i << 8);
            int buf = chunk >> 9, loc = chunk & 511;
            int r = loc >> 3, c = loc & 7;
            *(uint4*)((buf ? sV : sK) + r * 128 + c * 16) = pf[i];
        }
    };

    issue(t0); commit();
    for (int ti = 0; ti < len; ++ti) {
        __syncthreads();
        if (ti + 1 < len) issue(t0 + ti + 1);
        int tg  = t0 + ti;
        int kv0 = tg << 6;

        // ---- QK^T (swapped: D[kv][q]) ----
        f32x4 p[4];
#pragma unroll
        for (int st = 0; st < 4; ++st) {
            bf16x8 ka0 = *(const bf16x8*)(sK + st * 2048 + lq * 128 + ka_off0);
            bf16x8 ka1 = *(const bf16x8*)(sK + st * 2048 + lq * 128 + ka_off1);
            f32x4 d = (f32x4){0.f, 0.f, 0.f, 0.f};
            d = __builtin_amdgcn_mfma_f32_16x16x32_bf16(ka0, qb0, d, 0, 0, 0);
            d = __builtin_amdgcn_mfma_f32_16x16x32_bf16(ka1, qb1, d, 0, 0, 0);
            p[st] = d;
        }

        // ---- mask + diagonal substitution (only tiles >= chk0) ----
        if (tg >= chk0) {
            int n_l = qbw + lq;
#pragma unroll
            for (int st = 0; st < 4; ++st)
#pragma unroll
                for (int r = 0; r < 4; ++r) {
                    int kv = kv0 + st * 16 + 4 * h + r;
                    float dd = p[st][r];
                    if (kv > n_l)           dd = -1e30f;
                    else if (kv == n_l)     dd = diag2_l;
                    else if (kv == n_l - 1) dd = diag1_l;
                    p[st][r] = dd;
                }
        }

        // ---- online softmax with defer-rescale (THR=5) ----
        float tmax = -1e30f;
#pragma unroll
        for (int st = 0; st < 4; ++st)
#pragma unroll
            for (int r = 0; r < 4; ++r) tmax = fmaxf(tmax, p[st][r]);
        tmax = fmaxf(tmax, __shfl_xor(tmax, 16, 64));
        tmax = fmaxf(tmax, __shfl_xor(tmax, 32, 64));
        if (!__all(tmax <= m_run + 5.0f)) {
            float m_new = fmaxf(m_run, tmax);
            float alpha = __expf(m_run - m_new);
            denom *= alpha;
            m_run = m_new;
#pragma unroll
            for (int r = 0; r < 4; ++r) {
                float ar = __shfl(alpha, 4 * h + r, 64);
                of[0][r] *= ar; of[1][r] *= ar; of[2][r] *= ar; of[3][r] *= ar;
            }
        }
        float lsum = 0.f;
#pragma unroll
        for (int st = 0; st < 4; ++st)
#pragma unroll
            for (int r = 0; r < 4; ++r) {
                float e = __expf(p[st][r] - m_run);
                p[st][r] = e;
                lsum += e;
            }
        lsum += __shfl_xor(lsum, 16, 64);
        lsum += __shfl_xor(lsum, 32, 64);
        denom += lsum;

        // ---- P -> bf16 into per-wave LDS ----
#pragma unroll
        for (int st = 0; st < 4; ++st) {
            uint2 uu;
            uu.x = pk2(p[st][0], p[st][1]);
            uu.y = pk2(p[st][2], p[st][3]);
            int chunk = (st << 1) + (h >> 1);
            *(uint2*)(sP + pr_base + ((chunk ^ l7) << 4) + ((h & 1) << 3)) = uu;
        }
        asm volatile("s_waitcnt lgkmcnt(0)" ::: "memory");
        __builtin_amdgcn_sched_barrier(0);

        // ---- PV ----
#pragma unroll
        for (int kk = 0; kk < 2; ++kk) {
            int koff = kk ? ka_off1 : ka_off0;
            bf16x8 pa = *(const bf16x8*)(sP + pr_base + koff);
#pragma unroll
            for (int ft = 0; ft < 4; ++ft) {
                bf16x8 vb = *(const bf16x8*)(sV + ft * 2048 + lq * 128 + koff);
                of[ft] = __builtin_amdgcn_mfma_f32_16x16x32_bf16(pa, vb, of[ft], 0, 0, 0);
            }
        }
        __syncthreads();
        if (ti + 1 < len) commit();
    }

    // ---- write partials ----
    int gslot = bh * NSLOT + slot;
    if (h == 0) {
        pM[gslot * 64 + w * 16 + lq] = m_run;
        pL[gslot * 64 + w * 16 + lq] = denom;
    }
    float* po = pO + (((size_t)gslot * 64 + w * 16) << 6);
#pragma unroll
    for (int r = 0; r < 4; ++r)
#pragma unroll
        for (int ft = 0; ft < 4; ++ft)
            po[((4 * h + r) << 6) + ft * 16 + lq] = of[ft][r];
}

// ---------------------------------------------------------------------------
// Kernel 3: merge partials + diagonal value corrections + final write.
// Block = (bh, j). 512 blocks; thread -> (row, 16-f group).
// ---------------------------------------------------------------------------
__global__ __launch_bounds__(256) void merge_kernel(
    const float* __restrict__ pM, const float* __restrict__ pL,
    const float* __restrict__ pO,
    const float* __restrict__ dg1, const float* __restrict__ dg2,
    const float* __restrict__ valg, const int* __restrict__ ids,
    const float* __restrict__ emb, float* __restrict__ outg)
{
    int pid = blockIdx.x;
    int bh = pid & 31, j = pid >> 5;
    int nc = (j >> 2) + 1;
    int t = threadIdx.x;
    int rloc = t >> 2, fg = t & 3;
    int n = (j << 6) + rloc;
    int f0 = fg << 4;
    size_t hb = (size_t)bh * NSEQ * HD;

    int gs[4]; float mc[4];
    float m_g = -3e30f;
    for (int c = 0; c < nc; ++c) {
        gs[c] = bh * NSLOT + IDX[(j << 2) | c];
        mc[c] = pM[gs[c] * 64 + rloc];
        m_g = fmaxf(m_g, mc[c]);
    }
    float D = 0.f;
    f32x4 a0 = (f32x4){0.f,0.f,0.f,0.f}, a1 = a0, a2 = a0, a3 = a0;
    for (int c = 0; c < nc; ++c) {
        float wc = __expf(mc[c] - m_g);
        D += pL[gs[c] * 64 + rloc] * wc;
        const float* po = pO + (((size_t)gs[c] * 64 + rloc) << 6) + f0;
        a0 += wc * *(const f32x4*)(po);
        a1 += wc * *(const f32x4*)(po + 4);
        a2 += wc * *(const f32x4*)(po + 8);
        a3 += wc * *(const f32x4*)(po + 12);
    }
    float inv = 1.0f / D;
    float d2 = dg2[bh * NSEQ + n], d1 = dg1[bh * NSEQ + n];
    float p2 = __expf(d2 - m_g) * inv;
    float p1 = (n >= 1) ? __expf(d1 - m_g) * inv : 0.f;
    const int* idb = ids + (size_t)(bh >> 4) * NSEQ;
    int id_n = idb[n];
    float e8  = emb[(size_t)id_n * 10 + 8];
    float e9  = emb[(size_t)id_n * 10 + 9];
    float e9p = (n >= 1) ? emb[(size_t)idb[n - 1] * 10 + 9] : 0.f;
    float ca = -(p2 * e8 + p1 * e9p);
    float cb = -p2 * e9;

    a0 *= inv; a1 *= inv; a2 *= inv; a3 *= inv;
    if (n + 1 < NSEQ) {
        const float* v1 = valg + hb + (size_t)(n + 1) * HD + f0;
        a0 += ca * *(const f32x4*)(v1);
        a1 += ca * *(const f32x4*)(v1 + 4);
        a2 += ca * *(const f32x4*)(v1 + 8);
        a3 += ca * *(const f32x4*)(v1 + 12);
    }
    if (n + 2 < NSEQ) {
        const float* v2 = valg + hb + (size_t)(n + 2) * HD + f0;
        a0 += cb * *(const f32x4*)(v2);
        a1 += cb * *(const f32x4*)(v2 + 4);
        a2 += cb * *(const f32x4*)(v2 + 8);
        a3 += cb * *(const f32x4*)(v2 + 12);
    }
    float* o = outg + hb + (size_t)n * HD + f0;
    *(f32x4*)(o)      = a0;
    *(f32x4*)(o + 4)  = a1;
    *(f32x4*)(o + 8)  = a2;
    *(f32x4*)(o + 12) = a3;
}

extern "C" void kernel_launch(void* const* d_in, const int* in_sizes, int n_in,
                              void* d_out, int out_size, void* d_ws, size_t ws_size,
                              hipStream_t stream)
{
    const int*   ids = (const int*)  d_in[0];
    const float* q   = (const float*)d_in[1];
    const float* key = (const float*)d_in[2];
    const float* val = (const float*)d_in[3];
    const float* emb = (const float*)d_in[4];
    float* out = (float*)d_out;

    char* w = (char*)d_ws;
    unsigned short* kc  = (unsigned short*)(w);                     // 4 MB
    unsigned short* vcT = (unsigned short*)(w + (4u << 20));        // 4 MB
    float* dg1 = (float*)(w + 8388608);                             // 128 KB
    float* dg2 = (float*)(w + 8519680);                             // 128 KB
    float* pM  = (float*)(w + 8650752);                             // 320 KB
    float* pL  = (float*)(w + 8978432);                             // 320 KB
    float* pO  = (float*)(w + 9306112);                             // 20 MB

    conv_kernel<<<1024, 256, 0, stream>>>(ids, key, val, q, emb, kc, vcT, dg1, dg2);
    attn_kernel<<<32 * NSLOT, 256, 0, stream>>>(q, kc, vcT, dg1, dg2, pM, pL, pO);
    merge_kernel<<<512, 256, 0, stream>>>(pM, pL, pO, dg1, dg2, val, ids, emb, out);
}